// Round 1
// baseline (916.291 us; speedup 1.0000x reference)
//
#include <hip/hip_runtime.h>
#include <cstdint>
#include <cstddef>

#define DI __device__ __forceinline__

typedef short bf16x8 __attribute__((ext_vector_type(8)));
typedef float f32x4  __attribute__((ext_vector_type(4)));
typedef _Float16 half2v __attribute__((ext_vector_type(2)));

typedef const uint32_t __attribute__((address_space(1)))* gptr_t;
typedef uint32_t       __attribute__((address_space(3)))* lptr_t;

DI void load_lds16(const void* g, void* l_wave_uniform) {
#if __has_builtin(__builtin_amdgcn_global_load_lds)
  __builtin_amdgcn_global_load_lds((gptr_t)g, (lptr_t)l_wave_uniform, 16, 0, 0);
#else
  int lane = threadIdx.x & 63;
  *(uint4*)((char*)l_wave_uniform + lane * 16) = *(const uint4*)g;
#endif
}

DI ushort f2bf(float f) {  // round-to-nearest-even fp32 -> bf16
  uint32_t u = __builtin_bit_cast(uint32_t, f);
  u += 0x7fffu + ((u >> 16) & 1u);
  return (ushort)(u >> 16);
}

DI half2v h2cast(uint32_t u) { return __builtin_bit_cast(half2v, u); }

#if __has_builtin(__builtin_amdgcn_fdot2)
#define FDOT2(a, b, c) __builtin_amdgcn_fdot2((a), (b), (c), false)
#else
DI float fdot2_fb(half2v a, half2v b, float c) {
  return c + (float)a.x * (float)b.x + (float)a.y * (float)b.y;
}
#define FDOT2(a, b, c) fdot2_fb((a), (b), (c))
#endif

// ---------------------------------------------------------------------------
// Weight conversion kernels
// ---------------------------------------------------------------------------

// W1cat[1536][1024] bf16: rows 0..767 = Wih1, rows 768..1535 = Wih2[:,256:1280]
__global__ void cvt_w1cat(const float* __restrict__ W1, const float* __restrict__ W2,
                          ushort* __restrict__ dst) {
  int idx = blockIdx.x * 256 + threadIdx.x;   // 0 .. 393215
  int e = idx * 4;
  int row = e >> 10;
  int col = e & 1023;
  const float* src = (row < 768) ? (W1 + (size_t)row * 1024 + col)
                                 : (W2 + (size_t)(row - 768) * 1280 + 256 + col);
  float4 f = *(const float4*)src;
  ushort4 o; o.x = f2bf(f.x); o.y = f2bf(f.y); o.z = f2bf(f.z); o.w = f2bf(f.w);
  *(ushort4*)(dst + e) = o;
}

// Wd_bf16 padded [10112][256]
__global__ void cvt_wd(const float* __restrict__ Wd, ushort* __restrict__ dst) {
  int idx = blockIdx.x * 256 + threadIdx.x;   // 0 .. 647167
  int e = idx * 4;
  int row = e >> 8;
  int col = e & 255;
  ushort4 o;
  if (row < 10000) {
    float4 f = *(const float4*)(Wd + (size_t)row * 256 + col);
    o.x = f2bf(f.x); o.y = f2bf(f.y); o.z = f2bf(f.z); o.w = f2bf(f.w);
  } else {
    o.x = 0; o.y = 0; o.z = 0; o.w = 0;
  }
  *(ushort4*)(dst + e) = o;
}

// Whh[768][256] fp32 -> packed f16 pairs [768][128] u32
__global__ void cvt_whh(const float* __restrict__ W, uint32_t* __restrict__ dst) {
  int idx = blockIdx.x * 256 + threadIdx.x;   // 0 .. 98303
  int row = idx >> 7;
  int p = idx & 127;
  float2 f = *(const float2*)(W + (size_t)row * 256 + p * 2);
  half2v h; h.x = (_Float16)f.x; h.y = (_Float16)f.y;
  dst[idx] = __builtin_bit_cast(uint32_t, h);
}

// emb gather: row r = t*B+b, E[token[r]] fp32 -> bf16 [8192][1024]
__global__ void gather_emb(const int* __restrict__ tok, const float* __restrict__ E,
                           ushort* __restrict__ emb) {
  int row = blockIdx.x;
  int t = threadIdx.x;          // 0..255, 4 elems each
  int v = tok[row];
  float4 f = *((const float4*)(E + (size_t)v * 1024) + t);
  ushort4 o; o.x = f2bf(f.x); o.y = f2bf(f.y); o.z = f2bf(f.z); o.w = f2bf(f.w);
  *((ushort4*)(emb + (size_t)row * 1024) + t) = o;
}

// ---------------------------------------------------------------------------
// GEMM: C[M,Nout] = A[M,K] * B[Npad,K]^T (+bias).  A,B bf16 K-contig, C fp32.
// BM=BN=128, BK=64, 256 threads (4 waves), each wave a 64x64 subtile.
// ---------------------------------------------------------------------------
template <bool BIAS, bool GUARD>
__global__ __launch_bounds__(256) void gemm_bt(
    const ushort* __restrict__ A, const ushort* __restrict__ B,
    float* __restrict__ C, const float* __restrict__ bias, int M, int K, int Nout) {
  __shared__ __align__(16) ushort As[128 * 64];
  __shared__ __align__(16) ushort Bs[128 * 64];
  const int t = threadIdx.x;
  const int wave = t >> 6, lane = t & 63;
  const int m0 = blockIdx.x * 128, n0 = blockIdx.y * 128;
  const int RM = (wave >> 1) * 64, RN = (wave & 1) * 64;
  const int lm = lane & 15, kg = lane >> 4;   // kg in 0..3

  f32x4 acc[4][4] = {};

  for (int k0 = 0; k0 < K; k0 += 64) {
#pragma unroll
    for (int i = 0; i < 4; ++i) {
      int off = i * 4096 + t * 16;       // byte offset within 16KB tile
      int row = off >> 7;                // /128 bytes per row
      int colb = off & 127;
      int ub = i * 4096 + wave * 1024;   // wave-uniform LDS byte base
      const ushort* ga = A + (size_t)(m0 + row) * K + k0 + (colb >> 1);
      load_lds16(ga, (char*)As + ub);
      const ushort* gb = B + (size_t)(n0 + row) * K + k0 + (colb >> 1);
      load_lds16(gb, (char*)Bs + ub);
    }
    __syncthreads();
#pragma unroll
    for (int kk = 0; kk < 64; kk += 32) {
      bf16x8 af[4], bfr[4];
#pragma unroll
      for (int i = 0; i < 4; ++i) {
        af[i]  = *(const bf16x8*)(As + (RM + i * 16 + lm) * 64 + kk + kg * 8);
        bfr[i] = *(const bf16x8*)(Bs + (RN + i * 16 + lm) * 64 + kk + kg * 8);
      }
#pragma unroll
      for (int i = 0; i < 4; ++i)
#pragma unroll
        for (int j = 0; j < 4; ++j)
          acc[i][j] = __builtin_amdgcn_mfma_f32_16x16x32_bf16(af[i], bfr[j], acc[i][j], 0, 0, 0);
    }
    __syncthreads();
  }

  const int rg = lane >> 4;   // row group 0..3
#pragma unroll
  for (int i = 0; i < 4; ++i) {
    int grow = m0 + RM + i * 16 + rg * 4;
#pragma unroll
    for (int j = 0; j < 4; ++j) {
      int gcol = n0 + RN + j * 16 + lm;
      if (GUARD && gcol >= Nout) continue;
      float bv = BIAS ? bias[gcol] : 0.f;
#pragma unroll
      for (int r = 0; r < 4; ++r)
        C[(size_t)(grow + r) * Nout + gcol] = acc[i][j][r] + bv;
    }
  }
}

// ---------------------------------------------------------------------------
// GRU scan: one 768-thread block per batch element; recurrent weights
// register-resident as packed f16; h in LDS as packed half2.
// Thread j owns gate row j (0..255 r, 256..511 z, 512..767 n).
// ---------------------------------------------------------------------------
__global__ __launch_bounds__(768, 3) void gru_scan(
    const uint32_t* __restrict__ Wpk,      // [768][128] f16-pairs of Whh
    const float* __restrict__ xg_all,      // [8192][1536] fp32 input gates
    int xg_off,
    const float* __restrict__ bih, const float* __restrict__ bhh,
    const float* __restrict__ Wih2,        // gru2 only: [768][1280] fp32 (else null)
    const float* __restrict__ h1in,        // gru2 only: [64][256] fp32
    float* __restrict__ hfin_ws,           // gru1: h1 scratch (else null)
    float* __restrict__ hfin_out,          // gru1: d_out h1 region (else null)
    ushort* __restrict__ preds)            // gru2: bf16 [8192][256] (else null)
{
  const int b = blockIdx.x;
  const int j = threadIdx.x;
  __shared__ __align__(16) uint32_t hpk[128];
  __shared__ float hf[256];
  __shared__ float rz[512];

  // preload recurrent weight row (256 f16 = 128 u32 = 32 uint4)
  uint4 w[32];
  {
    const uint4* wp = (const uint4*)(Wpk + (size_t)j * 128);
#pragma unroll
    for (int i = 0; i < 32; ++i) w[i] = wp[i];
  }
  float xbase = bih[j];
  const float bhhj = bhh[j];
  if (Wih2) {  // xg2_base = bih2 + Wih2[:, :256] @ h1
    const float4* wr = (const float4*)(Wih2 + (size_t)j * 1280);
    const float4* hb = (const float4*)(h1in + b * 256);
    float s = 0.f;
#pragma unroll 4
    for (int k = 0; k < 64; ++k) {
      float4 a = wr[k], c = hb[k];
      s += a.x * c.x + a.y * c.y + a.z * c.z + a.w * c.w;
    }
    xbase += s;
  }
  if (j < 128) hpk[j] = 0u;
  if (j < 256) hf[j] = 0.f;
  __syncthreads();

  for (int t = 0; t < 128; ++t) {
    float a0 = 0.f, a1 = 0.f, a2 = 0.f, a3 = 0.f;
#pragma unroll
    for (int i = 0; i < 32; ++i) {
      uint4 hv = ((const uint4*)hpk)[i];
      a0 = FDOT2(h2cast(w[i].x), h2cast(hv.x), a0);
      a1 = FDOT2(h2cast(w[i].y), h2cast(hv.y), a1);
      a2 = FDOT2(h2cast(w[i].z), h2cast(hv.z), a2);
      a3 = FDOT2(h2cast(w[i].w), h2cast(hv.w), a3);
    }
    float hg = (a0 + a1) + (a2 + a3) + bhhj;
    float xgv = xg_all[(size_t)(t * 64 + b) * 1536 + xg_off + j] + xbase;

    if (j < 512) rz[j] = 1.f / (1.f + __expf(-(xgv + hg)));
    __syncthreads();
    if (j >= 512) {
      int j2 = j - 512;
      float r = rz[j2], z = rz[256 + j2];
      float x2 = xgv + r * hg;
      x2 = fminf(fmaxf(x2, -15.f), 15.f);
      float e = __expf(-2.f * x2);
      float n = (1.f - e) / (1.f + e);
      float hnew = (1.f - z) * n + z * hf[j2];
      hf[j2] = hnew;
      if (preds) preds[(size_t)(t * 64 + b) * 256 + j2] = f2bf(hnew);
    }
    __syncthreads();
    if (j < 128) {
      half2v hh; hh.x = (_Float16)hf[2 * j]; hh.y = (_Float16)hf[2 * j + 1];
      hpk[j] = __builtin_bit_cast(uint32_t, hh);
    }
    __syncthreads();
  }

  if (j < 256) {
    if (hfin_ws)  hfin_ws[b * 256 + j] = hf[j];
    if (hfin_out) hfin_out[b * 256 + j] = hf[j];
  }
}

// ---------------------------------------------------------------------------
extern "C" void kernel_launch(void* const* d_in, const int* in_sizes, int n_in,
                              void* d_out, int out_size, void* d_ws, size_t ws_size,
                              hipStream_t stream) {
  const int*   tokens = (const int*)d_in[0];
  const float* E      = (const float*)d_in[1];
  const float* Wih1   = (const float*)d_in[2];
  const float* Whh1   = (const float*)d_in[3];
  const float* bih1   = (const float*)d_in[4];
  const float* bhh1   = (const float*)d_in[5];
  const float* Wih2   = (const float*)d_in[6];
  const float* Whh2   = (const float*)d_in[7];
  const float* bih2   = (const float*)d_in[8];
  const float* bhh2   = (const float*)d_in[9];
  // d_in[10..14]: Wh, bh, Wi, bi, w_att — provably unused (softmax sums to 1,
  // h1 is t-invariant => state == h1 exactly).
  const float* Wd     = (const float*)d_in[15];
  const float* bd     = (const float*)d_in[16];
  float* out = (float*)d_out;

  char* ws = (char*)d_ws;
  ushort*   emb   = (ushort*)  (ws + 0);          // 16,777,216 B
  ushort*   w1cat = (ushort*)  (ws + 16777216);   //  3,145,728 B
  float*    xg    = (float*)   (ws + 19922944);   // 50,331,648 B
  ushort*   wdb   = (ushort*)  (ws + 70254592);   //  5,177,344 B
  uint32_t* whh1p = (uint32_t*)(ws + 75431936);   //    393,216 B
  uint32_t* whh2p = (uint32_t*)(ws + 75825152);   //    393,216 B
  float*    h1    = (float*)   (ws + 76218368);   //     65,536 B
  ushort*   preds = (ushort*)  (ws + 76283904);   //  4,194,304 B

  cvt_w1cat<<<1536, 256, 0, stream>>>(Wih1, Wih2, w1cat);
  cvt_wd<<<2528, 256, 0, stream>>>(Wd, wdb);
  cvt_whh<<<384, 256, 0, stream>>>(Whh1, whh1p);
  cvt_whh<<<384, 256, 0, stream>>>(Whh2, whh2p);
  gather_emb<<<8192, 256, 0, stream>>>(tokens, E, emb);

  dim3 g1(64, 12);   // [8192 x 1536 x 1024]
  gemm_bt<false, false><<<g1, 256, 0, stream>>>(emb, w1cat, xg, nullptr, 8192, 1024, 1536);

  gru_scan<<<64, 768, 0, stream>>>(whh1p, xg, 0, bih1, bhh1,
                                   nullptr, nullptr, h1, out + 81920000, nullptr);
  gru_scan<<<64, 768, 0, stream>>>(whh2p, xg, 768, bih2, bhh2,
                                   Wih2, h1, nullptr, nullptr, preds);

  dim3 g2(64, 79);   // [8192 x 10112(pad of 10000) x 256]
  gemm_bt<true, true><<<g2, 256, 0, stream>>>(preds, wdb, out, bd, 8192, 256, 10000);
}

// Round 2
// 887.379 us; speedup vs baseline: 1.0326x; 1.0326x over previous
//
#include <hip/hip_runtime.h>
#include <cstdint>
#include <cstddef>

#define DI __device__ __forceinline__

typedef short bf16x8 __attribute__((ext_vector_type(8)));
typedef float f32x4  __attribute__((ext_vector_type(4)));
typedef _Float16 half2v __attribute__((ext_vector_type(2)));

typedef const uint32_t __attribute__((address_space(1)))* gptr_t;
typedef uint32_t       __attribute__((address_space(3)))* lptr_t;

DI void load_lds16(const void* g, void* l_wave_uniform) {
#if __has_builtin(__builtin_amdgcn_global_load_lds)
  __builtin_amdgcn_global_load_lds((gptr_t)g, (lptr_t)l_wave_uniform, 16, 0, 0);
#else
  int lane = threadIdx.x & 63;
  *(uint4*)((char*)l_wave_uniform + lane * 16) = *(const uint4*)g;
#endif
}

DI ushort f2bf(float f) {  // round-to-nearest-even fp32 -> bf16
  uint32_t u = __builtin_bit_cast(uint32_t, f);
  u += 0x7fffu + ((u >> 16) & 1u);
  return (ushort)(u >> 16);
}

DI half2v h2cast(uint32_t u) { return __builtin_bit_cast(half2v, u); }

#if __has_builtin(__builtin_amdgcn_fdot2)
#define FDOT2(a, b, c) __builtin_amdgcn_fdot2((a), (b), (c), false)
#else
DI float fdot2_fb(half2v a, half2v b, float c) {
  return c + (float)a.x * (float)b.x + (float)a.y * (float)b.y;
}
#define FDOT2(a, b, c) fdot2_fb((a), (b), (c))
#endif

// ---------------------------------------------------------------------------
// Weight conversion kernels
// ---------------------------------------------------------------------------

// W1cat[1536][1024] bf16: rows 0..767 = Wih1, rows 768..1535 = Wih2[:,256:1280]
__global__ void cvt_w1cat(const float* __restrict__ W1, const float* __restrict__ W2,
                          ushort* __restrict__ dst) {
  int idx = blockIdx.x * 256 + threadIdx.x;   // 0 .. 393215
  int e = idx * 4;
  int row = e >> 10;
  int col = e & 1023;
  const float* src = (row < 768) ? (W1 + (size_t)row * 1024 + col)
                                 : (W2 + (size_t)(row - 768) * 1280 + 256 + col);
  float4 f = *(const float4*)src;
  ushort4 o; o.x = f2bf(f.x); o.y = f2bf(f.y); o.z = f2bf(f.z); o.w = f2bf(f.w);
  *(ushort4*)(dst + e) = o;
}

// Wd_bf16 padded [10112][256]
__global__ void cvt_wd(const float* __restrict__ Wd, ushort* __restrict__ dst) {
  int idx = blockIdx.x * 256 + threadIdx.x;   // 0 .. 647167
  int e = idx * 4;
  int row = e >> 8;
  int col = e & 255;
  ushort4 o;
  if (row < 10000) {
    float4 f = *(const float4*)(Wd + (size_t)row * 256 + col);
    o.x = f2bf(f.x); o.y = f2bf(f.y); o.z = f2bf(f.z); o.w = f2bf(f.w);
  } else {
    o.x = 0; o.y = 0; o.z = 0; o.w = 0;
  }
  *(ushort4*)(dst + e) = o;
}

// Whh[768][256] fp32 -> packed f16 pairs [768][128] u32
__global__ void cvt_whh(const float* __restrict__ W, uint32_t* __restrict__ dst) {
  int idx = blockIdx.x * 256 + threadIdx.x;   // 0 .. 98303
  int row = idx >> 7;
  int p = idx & 127;
  float2 f = *(const float2*)(W + (size_t)row * 256 + p * 2);
  half2v h; h.x = (_Float16)f.x; h.y = (_Float16)f.y;
  dst[idx] = __builtin_bit_cast(uint32_t, h);
}

// emb gather: row r = t*B+b, E[token[r]] fp32 -> bf16 [8192][1024]
__global__ void gather_emb(const int* __restrict__ tok, const float* __restrict__ E,
                           ushort* __restrict__ emb) {
  int row = blockIdx.x;
  int t = threadIdx.x;          // 0..255, 4 elems each
  int v = tok[row];
  float4 f = *((const float4*)(E + (size_t)v * 1024) + t);
  ushort4 o; o.x = f2bf(f.x); o.y = f2bf(f.y); o.z = f2bf(f.z); o.w = f2bf(f.w);
  *((ushort4*)(emb + (size_t)row * 1024) + t) = o;
}

// ---------------------------------------------------------------------------
// GEMM: C[M,Nout] = A[M,K] * B[Npad,K]^T (+bias).  A,B bf16 K-contig, C fp32.
// BM=BN=128, BK=64, 256 threads (4 waves), each wave a 64x64 subtile.
// LDS chunk-XOR swizzle: 16B chunk c of row r lives at physical chunk c^(r&7).
// Without it, fragment reads are 16-way bank-conflicted (rows stride 128B =
// exactly 32 banks); with it, 2-way max (free, m136).
// ---------------------------------------------------------------------------
template <bool BIAS, bool GUARD>
__global__ __launch_bounds__(256) void gemm_bt(
    const ushort* __restrict__ A, const ushort* __restrict__ B,
    float* __restrict__ C, const float* __restrict__ bias, int M, int K, int Nout) {
  __shared__ __align__(16) ushort As[128 * 64];
  __shared__ __align__(16) ushort Bs[128 * 64];
  const int t = threadIdx.x;
  const int wave = t >> 6, lane = t & 63;
  const int m0 = blockIdx.x * 128, n0 = blockIdx.y * 128;
  const int RM = (wave >> 1) * 64, RN = (wave & 1) * 64;
  const int lm = lane & 15, kg = lane >> 4;   // kg in 0..3

  f32x4 acc[4][4] = {};

  for (int k0 = 0; k0 < K; k0 += 64) {
#pragma unroll
    for (int i = 0; i < 4; ++i) {
      int off = i * 4096 + t * 16;       // byte offset within 16KB tile
      int row = off >> 7;                // /128 bytes per row
      int physc = (off >> 4) & 7;        // physical 16B chunk within row
      int gc = physc ^ (row & 7);        // logical (global) chunk
      int ub = i * 4096 + wave * 1024;   // wave-uniform LDS byte base
      const ushort* ga = A + (size_t)(m0 + row) * K + k0 + gc * 8;
      load_lds16(ga, (char*)As + ub);
      const ushort* gb = B + (size_t)(n0 + row) * K + k0 + gc * 8;
      load_lds16(gb, (char*)Bs + ub);
    }
    __syncthreads();
#pragma unroll
    for (int kk = 0; kk < 64; kk += 32) {
      const int lc = (kk >> 3) + kg;     // logical chunk for this fragment
      bf16x8 af[4], bfr[4];
#pragma unroll
      for (int i = 0; i < 4; ++i) {
        int ra = RM + i * 16 + lm;
        int rb = RN + i * 16 + lm;
        af[i]  = *(const bf16x8*)(As + ra * 64 + ((lc ^ (ra & 7)) << 3));
        bfr[i] = *(const bf16x8*)(Bs + rb * 64 + ((lc ^ (rb & 7)) << 3));
      }
#pragma unroll
      for (int i = 0; i < 4; ++i)
#pragma unroll
        for (int j = 0; j < 4; ++j)
          acc[i][j] = __builtin_amdgcn_mfma_f32_16x16x32_bf16(af[i], bfr[j], acc[i][j], 0, 0, 0);
    }
    __syncthreads();
  }

  const int rg = lane >> 4;   // row group 0..3
#pragma unroll
  for (int i = 0; i < 4; ++i) {
    int grow = m0 + RM + i * 16 + rg * 4;
#pragma unroll
    for (int j = 0; j < 4; ++j) {
      int gcol = n0 + RN + j * 16 + lm;
      if (GUARD && gcol >= Nout) continue;
      float bv = BIAS ? bias[gcol] : 0.f;
#pragma unroll
      for (int r = 0; r < 4; ++r)
        C[(size_t)(grow + r) * Nout + gcol] = acc[i][j][r] + bv;
    }
  }
}

// ---------------------------------------------------------------------------
// GRU scan: one 768-thread block per batch element; recurrent weights
// register-resident as packed f16 (w[32] uint4 = 128 VGPRs); h packed half2
// in LDS (broadcast reads). Thread j owns gate row j (r:0-255, z:256-511,
// n:512-767). n-threads keep h in a REGISTER (hprev); hpk repacked via
// intra-wave shfl (2 barriers/step). xg row software-prefetched 1 step ahead.
// ---------------------------------------------------------------------------
__global__ __launch_bounds__(768, 3) void gru_scan(
    const uint32_t* __restrict__ Wpk,      // [768][128] f16-pairs of Whh
    const float* __restrict__ xg_all,      // [8192][1536] fp32 input gates
    int xg_off,
    const float* __restrict__ bih, const float* __restrict__ bhh,
    const float* __restrict__ Wih2,        // gru2 only: [768][1280] fp32 (else null)
    const float* __restrict__ h1in,        // gru2 only: [64][256] fp32
    float* __restrict__ hfin_ws,           // gru1: h1 scratch (else null)
    float* __restrict__ hfin_out,          // gru1: d_out h1 region (else null)
    ushort* __restrict__ preds)            // gru2: bf16 [8192][256] (else null)
{
  const int b = blockIdx.x;
  const int j = threadIdx.x;
  __shared__ __align__(16) uint32_t hpk[128];
  __shared__ float rz[512];

  float xbase = bih[j];
  const float bhhj = bhh[j];
  if (Wih2) {  // xg2_base = bih2 + Wih2[:, :256] @ h1  (prologue, before w preload)
    const float4* wr = (const float4*)(Wih2 + (size_t)j * 1280);
    const float4* hb = (const float4*)(h1in + b * 256);
    float s = 0.f;
#pragma unroll 2
    for (int k = 0; k < 64; ++k) {
      float4 a = wr[k], c = hb[k];
      s += a.x * c.x + a.y * c.y + a.z * c.z + a.w * c.w;
    }
    xbase += s;
  }

  // preload recurrent weight row (256 f16 = 128 u32 = 32 uint4 = 128 VGPRs)
  uint4 w[32];
  {
    const uint4* wp = (const uint4*)(Wpk + (size_t)j * 128);
#pragma unroll
    for (int i = 0; i < 32; ++i) w[i] = wp[i];
  }

  if (j < 128) hpk[j] = 0u;
  float hprev = 0.f;              // n-threads: own h element
  __syncthreads();

  const float* xgp = xg_all + (size_t)b * 1536 + xg_off + j;
  float xcur = xgp[0];

  for (int t = 0; t < 128; ++t) {
    int tn = (t + 1 < 128) ? t + 1 : 127;
    float xnext = xgp[(size_t)tn * 98304];   // prefetch next step (64*1536)

    float a0 = 0.f, a1 = 0.f, a2 = 0.f, a3 = 0.f;
#pragma unroll
    for (int i = 0; i < 32; ++i) {
      uint4 hv = ((const uint4*)hpk)[i];     // wave-uniform broadcast
      a0 = FDOT2(h2cast(w[i].x), h2cast(hv.x), a0);
      a1 = FDOT2(h2cast(w[i].y), h2cast(hv.y), a1);
      a2 = FDOT2(h2cast(w[i].z), h2cast(hv.z), a2);
      a3 = FDOT2(h2cast(w[i].w), h2cast(hv.w), a3);
    }
    float hg = (a0 + a1) + (a2 + a3) + bhhj;
    float xgv = xcur + xbase;

    if (j < 512) rz[j] = 1.f / (1.f + __expf(-(xgv + hg)));
    __syncthreads();
    if (j >= 512) {
      int j2 = j - 512;
      float r = rz[j2], z = rz[256 + j2];
      float x2 = xgv + r * hg;
      x2 = fminf(fmaxf(x2, -15.f), 15.f);
      float e = __expf(-2.f * x2);
      float n = (1.f - e) / (1.f + e);
      float hnew = (1.f - z) * n + z * hprev;
      hprev = hnew;
      if (preds) preds[(size_t)(t * 64 + b) * 256 + j2] = f2bf(hnew);
      float hup = __shfl_down(hnew, 1);      // neighbor lane = h[j2+1]
      if (!(j2 & 1)) {
        half2v hh; hh.x = (_Float16)hnew; hh.y = (_Float16)hup;
        hpk[j2 >> 1] = __builtin_bit_cast(uint32_t, hh);
      }
    }
    xcur = xnext;
    __syncthreads();
  }

  if (j >= 512) {
    int j2 = j - 512;
    if (hfin_ws)  hfin_ws[b * 256 + j2] = hprev;
    if (hfin_out) hfin_out[b * 256 + j2] = hprev;
  }
}

// ---------------------------------------------------------------------------
extern "C" void kernel_launch(void* const* d_in, const int* in_sizes, int n_in,
                              void* d_out, int out_size, void* d_ws, size_t ws_size,
                              hipStream_t stream) {
  const int*   tokens = (const int*)d_in[0];
  const float* E      = (const float*)d_in[1];
  const float* Wih1   = (const float*)d_in[2];
  const float* Whh1   = (const float*)d_in[3];
  const float* bih1   = (const float*)d_in[4];
  const float* bhh1   = (const float*)d_in[5];
  const float* Wih2   = (const float*)d_in[6];
  const float* Whh2   = (const float*)d_in[7];
  const float* bih2   = (const float*)d_in[8];
  const float* bhh2   = (const float*)d_in[9];
  // d_in[10..14]: Wh, bh, Wi, bi, w_att — provably unused (softmax sums to 1,
  // h1 is t-invariant => state == h1 exactly).
  const float* Wd     = (const float*)d_in[15];
  const float* bd     = (const float*)d_in[16];
  float* out = (float*)d_out;

  char* ws = (char*)d_ws;
  ushort*   emb   = (ushort*)  (ws + 0);          // 16,777,216 B
  ushort*   w1cat = (ushort*)  (ws + 16777216);   //  3,145,728 B
  float*    xg    = (float*)   (ws + 19922944);   // 50,331,648 B
  ushort*   wdb   = (ushort*)  (ws + 70254592);   //  5,177,344 B
  uint32_t* whh1p = (uint32_t*)(ws + 75431936);   //    393,216 B
  uint32_t* whh2p = (uint32_t*)(ws + 75825152);   //    393,216 B
  float*    h1    = (float*)   (ws + 76218368);   //     65,536 B
  ushort*   preds = (ushort*)  (ws + 76283904);   //  4,194,304 B

  cvt_w1cat<<<1536, 256, 0, stream>>>(Wih1, Wih2, w1cat);
  cvt_wd<<<2528, 256, 0, stream>>>(Wd, wdb);
  cvt_whh<<<384, 256, 0, stream>>>(Whh1, whh1p);
  cvt_whh<<<384, 256, 0, stream>>>(Whh2, whh2p);
  gather_emb<<<8192, 256, 0, stream>>>(tokens, E, emb);

  dim3 g1(64, 12);   // [8192 x 1536 x 1024]
  gemm_bt<false, false><<<g1, 256, 0, stream>>>(emb, w1cat, xg, nullptr, 8192, 1024, 1536);

  gru_scan<<<64, 768, 0, stream>>>(whh1p, xg, 0, bih1, bhh1,
                                   nullptr, nullptr, h1, out + 81920000, nullptr);
  gru_scan<<<64, 768, 0, stream>>>(whh2p, xg, 768, bih2, bhh2,
                                   Wih2, h1, nullptr, nullptr, preds);

  dim3 g2(64, 79);   // [8192 x 10112(pad of 10000) x 256]
  gemm_bt<true, true><<<g2, 256, 0, stream>>>(preds, wdb, out, bd, 8192, 256, 10000);
}